// Round 4
// baseline (54975.916 us; speedup 1.0000x reference)
//
#include <hip/hip_runtime.h>
#include <hip/hip_bf16.h>
#include <stdint.h>

#define T_SEQ 8192
#define DIMS  2048
#define VOCAB 512
#define GS    ((size_t)VOCAB * DIMS)

typedef unsigned short u16;
typedef unsigned int   uint32;
typedef unsigned long long u64;

__device__ __forceinline__ float lo2f(uint32 u) { return __uint_as_float(u << 16); }
__device__ __forceinline__ float hi2f(uint32 u) { return __uint_as_float(u & 0xffff0000u); }

// DPP row_shr:N add (16-lane row, 0-fill OOB): after N=1,2,4,8 lane 15 (mod 16)
// holds its row's sum. ~8cy vs ds_bpermute ~35cy. Numerically validated in the
// round-2 run (passed, same absmax).
#define ROW_SHR_ADD(x, N)                                                          \
  x += __int_as_float(__builtin_amdgcn_update_dpp(                                 \
      0, __float_as_int(x), 0x110 + (N), 0xF, 0xF, true))

// ---------------------------------------------------------------- X = Wx.T + bx
__global__ __launch_bounds__(256) void k_build_x(const float* __restrict__ Wx,
                                                 const float* __restrict__ bx,
                                                 float* __restrict__ X) {
  int i = blockIdx.x * 256 + threadIdx.x;      // i = d*VOCAB + v
  int v = i & (VOCAB - 1);
  int d = i >> 9;
  X[(size_t)v * DIMS + d] = Wx[i] + bx[d];
}

// ---------------------------------------------------------------- G_g = X @ Wg.T + bwg
// Output interleaved by gate: G[(v*DIMS + j)*4 + gate].
__global__ __launch_bounds__(256) void k_gate_gemm(const float* __restrict__ X,
                                                   const float* __restrict__ Wg,
                                                   const float* __restrict__ bw,
                                                   float* __restrict__ Gout,
                                                   int gate) {
  __shared__ float Xs[32][64];
  __shared__ float Ws[32][64];
  const int v0 = blockIdx.y * 64;
  const int j0 = blockIdx.x * 64;
  const int tid = threadIdx.x;
  const int tx = tid & 15, ty = tid >> 4;
  float acc[4][4] = {{0.f}};
  for (int k0 = 0; k0 < DIMS; k0 += 32) {
    const int r = tid >> 2, q = tid & 3;
    {
      const float* src = X + (size_t)(v0 + r) * DIMS + k0 + q * 8;
      float4 a = ((const float4*)src)[0];
      float4 b = ((const float4*)src)[1];
      Xs[q*8+0][r]=a.x; Xs[q*8+1][r]=a.y; Xs[q*8+2][r]=a.z; Xs[q*8+3][r]=a.w;
      Xs[q*8+4][r]=b.x; Xs[q*8+5][r]=b.y; Xs[q*8+6][r]=b.z; Xs[q*8+7][r]=b.w;
      const float* wsrc = Wg + (size_t)(j0 + r) * DIMS + k0 + q * 8;
      float4 c = ((const float4*)wsrc)[0];
      float4 e = ((const float4*)wsrc)[1];
      Ws[q*8+0][r]=c.x; Ws[q*8+1][r]=c.y; Ws[q*8+2][r]=c.z; Ws[q*8+3][r]=c.w;
      Ws[q*8+4][r]=e.x; Ws[q*8+5][r]=e.y; Ws[q*8+6][r]=e.z; Ws[q*8+7][r]=e.w;
    }
    __syncthreads();
    #pragma unroll
    for (int k = 0; k < 32; ++k) {
      float xa[4], wb[4];
      *(float4*)xa = *(const float4*)&Xs[k][ty*4];
      *(float4*)wb = *(const float4*)&Ws[k][tx*4];
      #pragma unroll
      for (int a = 0; a < 4; ++a)
        #pragma unroll
        for (int b = 0; b < 4; ++b)
          acc[a][b] = fmaf(xa[a], wb[b], acc[a][b]);
    }
    __syncthreads();
  }
  #pragma unroll
  for (int a = 0; a < 4; ++a)
    #pragma unroll
    for (int b = 0; b < 4; ++b)
      Gout[(((size_t)(v0 + ty*4 + a) * DIMS + j0 + tx*4 + b) << 2) + gate] =
          acc[a][b] + bw[j0 + tx*4 + b];
}

// ---------------------------------------------------------------- recurrence
// Round-7: EXACT round-1 structure (best: 18.7ms) + three local, hop-free edits
// on the publish critical path (round-3 calibrated: one publish->poll round
// trip ~= 4-5kcy; step = 1 round trip + ~1.5kcy compute/tail):
//  (T) tail shortened: intra-16 reduce via 4 DPP row_shr adds (sums land in
//      lanes 15/31/47/63), activations on those lanes in parallel, activated
//      scalars gathered to lane 15, which updates c and publishes. Replaces
//      4 dependent ds_bpermute + 3 gathers. ~150-250cy off the pre-publish
//      chain.
//  (P) publish via fire-and-forget __hip_atomic_exchange: executes at the
//      memory-side cache, keeps hbuf lines L3-resident instead of the
//      store-writethrough path (WRITE_SIZE 590MB = 16.7M x 32B sectors).
//  (W) rotating hs writer moved AFTER the publish (parity-safe until t+2
//      staging; reads h4[t&1] which next iteration does not touch) so the
//      writer block's 8 publishes are never delayed by its hs stores.
// Protocol (tags, parity double-buffer, selective-retry poll) unchanged.
template <typename HS> __device__ __forceinline__ void store_h4(HS* hs, size_t idx, float4 v);
template <> __device__ __forceinline__ void store_h4<float>(float* hs, size_t idx, float4 v) {
  *(float4*)(hs + idx) = v;
}
template <> __device__ __forceinline__ void store_h4<u16>(u16* hs, size_t idx, float4 v) {
  __hip_bfloat16 bx = __float2bfloat16(v.x);
  __hip_bfloat16 by = __float2bfloat16(v.y);
  __hip_bfloat16 bz = __float2bfloat16(v.z);
  __hip_bfloat16 bw = __float2bfloat16(v.w);
  ushort4 o;
  o.x = *reinterpret_cast<u16*>(&bx);
  o.y = *reinterpret_cast<u16*>(&by);
  o.z = *reinterpret_cast<u16*>(&bz);
  o.w = *reinterpret_cast<u16*>(&bw);
  *(ushort4*)(hs + idx) = o;
}

template <typename HS>
__global__ __launch_bounds__(512, 2) void k_lstm(
    const int* __restrict__ tokens,
    const float* __restrict__ G,
    uint32* hbuf,
    HS* __restrict__ hs,
    const float* __restrict__ Uf, const float* __restrict__ Ui,
    const float* __restrict__ Uc, const float* __restrict__ Uo,
    const float* __restrict__ bUf, const float* __restrict__ bUi,
    const float* __restrict__ bUc, const float* __restrict__ bUo) {
  __shared__ float4 h4[2][DIMS / 4];
  const int tid  = threadIdx.x;          // 0..511
  const int wave = tid >> 6;             // 0..7
  const int lane = tid & 63;
  const int gate = lane >> 4;            // 0..3 -> f,i,c,o
  const int sl   = lane & 15;            // k-split within gate group
  const int jr   = blockIdx.x * 8 + wave;

  const float* Ug = (gate == 0) ? Uf : (gate == 1) ? Ui : (gate == 2) ? Uc : Uo;
  const float4* urow = (const float4*)(Ug + (size_t)jr * DIMS);
  float4 w[32];
  #pragma unroll
  for (int i = 0; i < 32; ++i) w[i] = urow[sl + 16 * i];
  #pragma unroll
  for (int i = 0; i < 32; ++i)
    asm volatile("" : "+v"(w[i].x), "+v"(w[i].y), "+v"(w[i].z), "+v"(w[i].w));

  float creg = 0.f, bias = 0.f, gvp = 0.f;
  if (sl == 15) {  // lanes 15,31,47,63 own one gate each (reduce lands there)
    const float* Bg = (gate == 0) ? bUf : (gate == 1) ? bUi : (gate == 2) ? bUc : bUo;
    bias = Bg[jr];
    const int tok0 = tokens[0];
    gvp = G[((size_t)tok0 * DIMS + jr) * 4 + gate];
  }
  if (lane == 0) {
    // h0 = 0 with tag 0; buffer-1 tag 0 (!= 1, != poison 0xAA).
    __hip_atomic_store(&hbuf[jr], 0u, __ATOMIC_RELAXED, __HIP_MEMORY_SCOPE_AGENT);
    __hip_atomic_store(&hbuf[DIMS + jr], 0u, __ATOMIC_RELAXED, __HIP_MEMORY_SCOPE_AGENT);
  }

  #pragma unroll 1
  for (int t = 0; t < T_SEQ; ++t) {
    { // stage h_t: thread tid owns h[4*tid..4*tid+3]; poll tags, selective retry
      const u64* hsrc = (const u64*)(hbuf + (size_t)(t & 1) * DIMS) + 2 * tid;
      const uint32 want = (uint32)t & 0xFFu;
      u64 u0 = __hip_atomic_load(hsrc + 0, __ATOMIC_RELAXED, __HIP_MEMORY_SCOPE_AGENT);
      u64 u1 = __hip_atomic_load(hsrc + 1, __ATOMIC_RELAXED, __HIP_MEMORY_SCOPE_AGENT);
      for (;;) {
        const bool ok0 = ((((uint32)u0 ^ want) | ((uint32)(u0 >> 32) ^ want)) & 0xFFu) == 0u;
        const bool ok1 = ((((uint32)u1 ^ want) | ((uint32)(u1 >> 32) ^ want)) & 0xFFu) == 0u;
        if (ok0 && ok1) break;
        if (!ok0) u0 = __hip_atomic_load(hsrc + 0, __ATOMIC_RELAXED, __HIP_MEMORY_SCOPE_AGENT);
        if (!ok1) u1 = __hip_atomic_load(hsrc + 1, __ATOMIC_RELAXED, __HIP_MEMORY_SCOPE_AGENT);
      }
      h4[t & 1][tid] = make_float4(__uint_as_float((uint32)u0),
                                   __uint_as_float((uint32)(u0 >> 32)),
                                   __uint_as_float((uint32)u1),
                                   __uint_as_float((uint32)(u1 >> 32)));
    }
    __syncthreads();
    // one dot of length 2048, split: gate group reads all h, sub-lane covers 128 k
    const float4* hb = h4[t & 1];
    float4 a4 = make_float4(0.f, 0.f, 0.f, 0.f);
    #pragma unroll
    for (int i = 0; i < 32; ++i) {
      float4 hv = hb[sl + 16 * i];
      a4.x = fmaf(w[i].x, hv.x, a4.x);
      a4.y = fmaf(w[i].y, hv.y, a4.y);
      a4.z = fmaf(w[i].z, hv.z, a4.z);
      a4.w = fmaf(w[i].w, hv.w, a4.w);
    }
    float acc = (a4.x + a4.y) + (a4.z + a4.w);
    // (T) intra-16 reduce via DPP; gate sums land in lanes 15/31/47/63.
    ROW_SHR_ADD(acc, 1); ROW_SHR_ADD(acc, 2); ROW_SHR_ADD(acc, 4); ROW_SHR_ADD(acc, 8);
    float act = 0.f;
    if (sl == 15) {  // 4 activations in parallel; tanh(y)=2*sigmoid(2y)-1
      const float y = acc + bias + gvp;
      const float s = 1.f / (1.f + __expf((gate == 2) ? (-2.f * y) : (-y)));
      act = (gate == 2) ? (2.f * s - 1.f) : s;
    }
    const float aI = __shfl(act, 31, 64);
    const float aC = __shfl(act, 47, 64);
    const float aO = __shfl(act, 63, 64);
    if (lane == 15) {
      creg = act * creg + aI * aC;                 // f*c + i*c_new
      const float th = 1.f - 2.f / (1.f + __expf(2.f * creg));
      const float hv = aO * th;
      const uint32 tb = (__float_as_uint(hv) & 0xFFFFFF00u) | ((uint32)(t + 1) & 0xFFu);
      // (P) fire-and-forget swap: performed at the memory-side cache.
      (void)__hip_atomic_exchange(&hbuf[(size_t)((t + 1) & 1) * DIMS + jr], tb,
                                  __ATOMIC_RELAXED, __HIP_MEMORY_SCOPE_AGENT);
    }
    if (sl == 15) {                                // prefetch gate preact for t+1
      const int tn = (t + 1 < T_SEQ) ? t + 1 : T_SEQ - 1;
      gvp = G[((size_t)tokens[tn] * DIMS + jr) * 4 + gate];
    }
    // (W) rotating coalesced hs writer, post-publish (parity-safe until t+2).
    if ((int)blockIdx.x == (t & 255)) {
      float4 hv4 = h4[t & 1][tid];
      store_h4<HS>(hs, (size_t)t * DIMS + 4 * (size_t)tid, hv4);
    }
  }
}

// ---------------------------------------------------------------- logits = hs @ V.T + bv
template <typename HS> __device__ __forceinline__ void load8(const HS* p, float* o);
template <> __device__ __forceinline__ void load8<float>(const float* p, float* o) {
  float4 a = ((const float4*)p)[0], b = ((const float4*)p)[1];
  o[0]=a.x; o[1]=a.y; o[2]=a.z; o[3]=a.w; o[4]=b.x; o[5]=b.y; o[6]=b.z; o[7]=b.w;
}
template <> __device__ __forceinline__ void load8<u16>(const u16* p, float* o) {
  uint4 u = *(const uint4*)p;
  o[0]=lo2f(u.x); o[1]=hi2f(u.x); o[2]=lo2f(u.y); o[3]=hi2f(u.y);
  o[4]=lo2f(u.z); o[5]=hi2f(u.z); o[6]=lo2f(u.w); o[7]=hi2f(u.w);
}

template <typename HS>
__global__ __launch_bounds__(256) void k_out_gemm(const HS* __restrict__ hs,
                                                  const float* __restrict__ V,
                                                  const float* __restrict__ bvb,
                                                  float* __restrict__ logits) {
  __shared__ float As[32][64];
  __shared__ float Bs[32][128];
  const int t0 = blockIdx.x * 64;
  const int v0 = blockIdx.y * 128;
  const int tid = threadIdx.x;
  const int tx = tid & 15, ty = tid >> 4;
  float acc[4][8] = {{0.f}};
  for (int k0 = 0; k0 < DIMS; k0 += 32) {
    {
      const int r = tid >> 2, q = tid & 3;
      float o8[8];
      load8<HS>(hs + (size_t)(t0 + r) * DIMS + k0 + q * 8, o8);
      #pragma unroll
      for (int s = 0; s < 8; ++s) As[q*8+s][r] = o8[s];
      const int rb = tid >> 1, c0 = (tid & 1) * 2;
      #pragma unroll
      for (int c = 0; c < 2; ++c) {
        float p8[8];
        load8<float>(V + (size_t)(v0 + rb) * DIMS + k0 + (c0 + c) * 8, p8);
        #pragma unroll
        for (int s = 0; s < 8; ++s) Bs[(c0+c)*8+s][rb] = p8[s];
      }
    }
    __syncthreads();
    #pragma unroll
    for (int k = 0; k < 32; ++k) {
      float av[4], bw8[8];
      *(float4*)av = *(const float4*)&As[k][ty*4];
      *(float4*)&bw8[0] = *(const float4*)&Bs[k][tx*8];
      *(float4*)&bw8[4] = *(const float4*)&Bs[k][tx*8+4];
      #pragma unroll
      for (int a = 0; a < 4; ++a)
        #pragma unroll
        for (int b = 0; b < 8; ++b)
          acc[a][b] = fmaf(av[a], bw8[b], acc[a][b]);
    }
    __syncthreads();
  }
  #pragma unroll
  for (int a = 0; a < 4; ++a)
    #pragma unroll
    for (int b = 0; b < 8; ++b)
      logits[(size_t)(t0 + ty*4 + a) * VOCAB + v0 + tx*8 + b] =
          acc[a][b] + bvb[v0 + tx*8 + b];
}

// ---------------------------------------------------------------- log_softmax rows (in-place)
__global__ __launch_bounds__(256) void k_logsoftmax(float* __restrict__ logits) {
  const int t = blockIdx.x;
  const int tid = threadIdx.x;
  float* row = logits + (size_t)t * VOCAB;
  float x0 = row[tid], x1 = row[tid + 256];
  float m = fmaxf(x0, x1);
  #pragma unroll
  for (int d = 32; d; d >>= 1) m = fmaxf(m, __shfl_xor(m, d, 64));
  __shared__ float r1[4], r2[4];
  if ((tid & 63) == 0) r1[tid >> 6] = m;
  __syncthreads();
  m = fmaxf(fmaxf(r1[0], r1[1]), fmaxf(r1[2], r1[3]));
  float s = __expf(x0 - m) + __expf(x1 - m);
  #pragma unroll
  for (int d = 32; d; d >>= 1) s += __shfl_xor(s, d, 64);
  if ((tid & 63) == 0) r2[tid >> 6] = s;
  __syncthreads();
  s = r2[0] + r2[1] + r2[2] + r2[3];
  const float lse = m + __logf(s);
  row[tid] = x0 - lse;
  row[tid + 256] = x1 - lse;
}

// ----------------------------------------------------------------
extern "C" void kernel_launch(void* const* d_in, const int* in_sizes, int n_in,
                              void* d_out, int out_size, void* d_ws, size_t ws_size,
                              hipStream_t stream) {
  const int*   tokens = (const int*)d_in[0];
  const float* Wx  = (const float*)d_in[1];
  const float* bx  = (const float*)d_in[2];
  const float* Uf  = (const float*)d_in[3];
  const float* bUf = (const float*)d_in[4];
  const float* Wf  = (const float*)d_in[5];
  const float* bwf = (const float*)d_in[6];
  const float* Ui  = (const float*)d_in[7];
  const float* bUi = (const float*)d_in[8];
  const float* Wi  = (const float*)d_in[9];
  const float* bwi = (const float*)d_in[10];
  const float* Uc  = (const float*)d_in[11];
  const float* bUc = (const float*)d_in[12];
  const float* Wc  = (const float*)d_in[13];
  const float* bwc = (const float*)d_in[14];
  const float* Uo  = (const float*)d_in[15];
  const float* bUo = (const float*)d_in[16];
  const float* Wo  = (const float*)d_in[17];
  const float* bwo = (const float*)d_in[18];
  const float* V   = (const float*)d_in[19];
  const float* bv  = (const float*)d_in[20];

  char* ws = (char*)d_ws;
  float* X = (float*)ws;                                   // 4 MiB
  float* G = (float*)(ws + 4194304ull);                    // 16 MiB (gate-interleaved)
  uint32* hbuf = (uint32*)(ws + 20971520ull);              // 16 KiB (32 reserved)
  char* rest = ws + 21004288ull;
  const bool f32path = ws_size >= 88113152ull;             // + hs f32 (64 MiB)

  k_build_x<<<dim3((DIMS * VOCAB) / 256), dim3(256), 0, stream>>>(Wx, bx, X);
  dim3 gg(DIMS / 64, VOCAB / 64);
  k_gate_gemm<<<gg, dim3(256), 0, stream>>>(X, Wf, bwf, G, 0);
  k_gate_gemm<<<gg, dim3(256), 0, stream>>>(X, Wi, bwi, G, 1);
  k_gate_gemm<<<gg, dim3(256), 0, stream>>>(X, Wc, bwc, G, 2);
  k_gate_gemm<<<gg, dim3(256), 0, stream>>>(X, Wo, bwo, G, 3);

  float* logits = (float*)d_out;   // logits built in d_out, log_softmax in-place
  if (f32path) {
    float* hs = (float*)rest;
    k_lstm<float><<<dim3(256), dim3(512), 0, stream>>>(
        tokens, G, hbuf, hs, Uf, Ui, Uc, Uo, bUf, bUi, bUc, bUo);
    k_out_gemm<float><<<dim3(T_SEQ / 64, VOCAB / 128), dim3(256), 0, stream>>>(
        hs, V, bv, logits);
  } else {
    u16* hs = (u16*)rest;
    k_lstm<u16><<<dim3(256), dim3(512), 0, stream>>>(
        tokens, G, hbuf, hs, Uf, Ui, Uc, Uo, bUf, bUi, bUc, bUo);
    k_out_gemm<u16><<<dim3(T_SEQ / 64, VOCAB / 128), dim3(256), 0, stream>>>(
        hs, V, bv, logits);
  }
  k_logsoftmax<<<dim3(T_SEQ), dim3(256), 0, stream>>>(logits);
}

// Round 5
// 44147.260 us; speedup vs baseline: 1.2453x; 1.2453x over previous
//
#include <hip/hip_runtime.h>
#include <hip/hip_bf16.h>
#include <stdint.h>

#define T_SEQ 8192
#define DIMS  2048
#define VOCAB 512
#define GS    ((size_t)VOCAB * DIMS)

typedef unsigned short u16;
typedef unsigned int   uint32;
typedef unsigned long long u64;

__device__ __forceinline__ float lo2f(uint32 u) { return __uint_as_float(u << 16); }
__device__ __forceinline__ float hi2f(uint32 u) { return __uint_as_float(u & 0xffff0000u); }

// ---------------------------------------------------------------- X = Wx.T + bx
__global__ __launch_bounds__(256) void k_build_x(const float* __restrict__ Wx,
                                                 const float* __restrict__ bx,
                                                 float* __restrict__ X) {
  int i = blockIdx.x * 256 + threadIdx.x;      // i = d*VOCAB + v
  int v = i & (VOCAB - 1);
  int d = i >> 9;
  X[(size_t)v * DIMS + d] = Wx[i] + bx[d];
}

// ---------------------------------------------------------------- G_g = X @ Wg.T + bwg
// Output interleaved by gate: G[(v*DIMS + j)*4 + gate].
__global__ __launch_bounds__(256) void k_gate_gemm(const float* __restrict__ X,
                                                   const float* __restrict__ Wg,
                                                   const float* __restrict__ bw,
                                                   float* __restrict__ Gout,
                                                   int gate) {
  __shared__ float Xs[32][64];
  __shared__ float Ws[32][64];
  const int v0 = blockIdx.y * 64;
  const int j0 = blockIdx.x * 64;
  const int tid = threadIdx.x;
  const int tx = tid & 15, ty = tid >> 4;
  float acc[4][4] = {{0.f}};
  for (int k0 = 0; k0 < DIMS; k0 += 32) {
    const int r = tid >> 2, q = tid & 3;
    {
      const float* src = X + (size_t)(v0 + r) * DIMS + k0 + q * 8;
      float4 a = ((const float4*)src)[0];
      float4 b = ((const float4*)src)[1];
      Xs[q*8+0][r]=a.x; Xs[q*8+1][r]=a.y; Xs[q*8+2][r]=a.z; Xs[q*8+3][r]=a.w;
      Xs[q*8+4][r]=b.x; Xs[q*8+5][r]=b.y; Xs[q*8+6][r]=b.z; Xs[q*8+7][r]=b.w;
      const float* wsrc = Wg + (size_t)(j0 + r) * DIMS + k0 + q * 8;
      float4 c = ((const float4*)wsrc)[0];
      float4 e = ((const float4*)wsrc)[1];
      Ws[q*8+0][r]=c.x; Ws[q*8+1][r]=c.y; Ws[q*8+2][r]=c.z; Ws[q*8+3][r]=c.w;
      Ws[q*8+4][r]=e.x; Ws[q*8+5][r]=e.y; Ws[q*8+6][r]=e.z; Ws[q*8+7][r]=e.w;
    }
    __syncthreads();
    #pragma unroll
    for (int k = 0; k < 32; ++k) {
      float xa[4], wb[4];
      *(float4*)xa = *(const float4*)&Xs[k][ty*4];
      *(float4*)wb = *(const float4*)&Ws[k][tx*4];
      #pragma unroll
      for (int a = 0; a < 4; ++a)
        #pragma unroll
        for (int b = 0; b < 4; ++b)
          acc[a][b] = fmaf(xa[a], wb[b], acc[a][b]);
    }
    __syncthreads();
  }
  #pragma unroll
  for (int a = 0; a < 4; ++a)
    #pragma unroll
    for (int b = 0; b < 4; ++b)
      Gout[(((size_t)(v0 + ty*4 + a) * DIMS + j0 + tx*4 + b) << 2) + gate] =
          acc[a][b] + bw[j0 + tx*4 + b];
}

// ---------------------------------------------------------------- recurrence
// Round-8: EXACT round-1 kernel (best: 18.7ms) + ONE bounded edit:
//  (W) rotating hs writer moved AFTER the publish. Mechanism: each step the
//      writer block's 8 publisher lanes had one hs float4 store issued ahead
//      of their publish dword in program order; the step period is gated by
//      the max over all 2048 row publishes, so those 8 rows were
//      systematically late every step. Post-publish the writer is free.
//      Safety: h4[t&1] is only restaged (same block's LDS) at step t+2, and
//      the t+1 staging writes the OTHER parity buffer; the t+1 __syncthreads
//      cannot be passed until the writer thread finishes its ds_reads (the
//      compiler drains lgkmcnt before s_barrier). No race.
// Round-4 post-mortem pinned the 2.7x regression on the returning-atomic
// publish (global_atomic_swap must win exclusive ownership of a line held
// read-shared by 2048 pollers -> starved at the L3 slice) plus the DPP/lane-15
// tail restructure (also regressed in round 2). Both reverted: plain relaxed
// tagged store from lane 0, shfl_xor reduce, parallel activations on lanes
// 0/16/32/48.
template <typename HS> __device__ __forceinline__ void store_h4(HS* hs, size_t idx, float4 v);
template <> __device__ __forceinline__ void store_h4<float>(float* hs, size_t idx, float4 v) {
  *(float4*)(hs + idx) = v;
}
template <> __device__ __forceinline__ void store_h4<u16>(u16* hs, size_t idx, float4 v) {
  __hip_bfloat16 bx = __float2bfloat16(v.x);
  __hip_bfloat16 by = __float2bfloat16(v.y);
  __hip_bfloat16 bz = __float2bfloat16(v.z);
  __hip_bfloat16 bw = __float2bfloat16(v.w);
  ushort4 o;
  o.x = *reinterpret_cast<u16*>(&bx);
  o.y = *reinterpret_cast<u16*>(&by);
  o.z = *reinterpret_cast<u16*>(&bz);
  o.w = *reinterpret_cast<u16*>(&bw);
  *(ushort4*)(hs + idx) = o;
}

template <typename HS>
__global__ __launch_bounds__(512, 2) void k_lstm(
    const int* __restrict__ tokens,
    const float* __restrict__ G,
    uint32* hbuf,
    HS* __restrict__ hs,
    const float* __restrict__ Uf, const float* __restrict__ Ui,
    const float* __restrict__ Uc, const float* __restrict__ Uo,
    const float* __restrict__ bUf, const float* __restrict__ bUi,
    const float* __restrict__ bUc, const float* __restrict__ bUo) {
  __shared__ float4 h4[2][DIMS / 4];
  const int tid  = threadIdx.x;          // 0..511
  const int wave = tid >> 6;             // 0..7
  const int lane = tid & 63;
  const int gate = lane >> 4;            // 0..3 -> f,i,c,o
  const int sl   = lane & 15;            // k-split within gate group
  const int jr   = blockIdx.x * 8 + wave;

  const float* Ug = (gate == 0) ? Uf : (gate == 1) ? Ui : (gate == 2) ? Uc : Uo;
  const float4* urow = (const float4*)(Ug + (size_t)jr * DIMS);
  float4 w[32];
  #pragma unroll
  for (int i = 0; i < 32; ++i) w[i] = urow[sl + 16 * i];
  #pragma unroll
  for (int i = 0; i < 32; ++i)
    asm volatile("" : "+v"(w[i].x), "+v"(w[i].y), "+v"(w[i].z), "+v"(w[i].w));

  float creg = 0.f, bias = 0.f, gvp = 0.f;
  if (sl == 0) {   // lanes 0,16,32,48 own one gate each
    const float* Bg = (gate == 0) ? bUf : (gate == 1) ? bUi : (gate == 2) ? bUc : bUo;
    bias = Bg[jr];
    const int tok0 = tokens[0];
    gvp = G[((size_t)tok0 * DIMS + jr) * 4 + gate];
  }
  if (lane == 0) {
    // h0 = 0 with tag 0; buffer-1 tag 0 (!= 1, != poison 0xAA).
    __hip_atomic_store(&hbuf[jr], 0u, __ATOMIC_RELAXED, __HIP_MEMORY_SCOPE_AGENT);
    __hip_atomic_store(&hbuf[DIMS + jr], 0u, __ATOMIC_RELAXED, __HIP_MEMORY_SCOPE_AGENT);
  }

  #pragma unroll 1
  for (int t = 0; t < T_SEQ; ++t) {
    { // stage h_t: thread tid owns h[4*tid..4*tid+3]; poll tags, selective retry
      const u64* hsrc = (const u64*)(hbuf + (size_t)(t & 1) * DIMS) + 2 * tid;
      const uint32 want = (uint32)t & 0xFFu;
      u64 u0 = __hip_atomic_load(hsrc + 0, __ATOMIC_RELAXED, __HIP_MEMORY_SCOPE_AGENT);
      u64 u1 = __hip_atomic_load(hsrc + 1, __ATOMIC_RELAXED, __HIP_MEMORY_SCOPE_AGENT);
      for (;;) {
        const bool ok0 = ((((uint32)u0 ^ want) | ((uint32)(u0 >> 32) ^ want)) & 0xFFu) == 0u;
        const bool ok1 = ((((uint32)u1 ^ want) | ((uint32)(u1 >> 32) ^ want)) & 0xFFu) == 0u;
        if (ok0 && ok1) break;
        if (!ok0) u0 = __hip_atomic_load(hsrc + 0, __ATOMIC_RELAXED, __HIP_MEMORY_SCOPE_AGENT);
        if (!ok1) u1 = __hip_atomic_load(hsrc + 1, __ATOMIC_RELAXED, __HIP_MEMORY_SCOPE_AGENT);
      }
      h4[t & 1][tid] = make_float4(__uint_as_float((uint32)u0),
                                   __uint_as_float((uint32)(u0 >> 32)),
                                   __uint_as_float((uint32)u1),
                                   __uint_as_float((uint32)(u1 >> 32)));
    }
    __syncthreads();
    // one dot of length 2048, split: gate group reads all h, sub-lane covers 128 k
    const float4* hb = h4[t & 1];
    float4 a4 = make_float4(0.f, 0.f, 0.f, 0.f);
    #pragma unroll
    for (int i = 0; i < 32; ++i) {
      float4 hv = hb[sl + 16 * i];
      a4.x = fmaf(w[i].x, hv.x, a4.x);
      a4.y = fmaf(w[i].y, hv.y, a4.y);
      a4.z = fmaf(w[i].z, hv.z, a4.z);
      a4.w = fmaf(w[i].w, hv.w, a4.w);
    }
    float acc = (a4.x + a4.y) + (a4.z + a4.w);
    #pragma unroll
    for (int d = 1; d <= 8; d <<= 1) acc += __shfl_xor(acc, d, 64);
    // per-gate activation in parallel on lanes 0,16,32,48
    float act = 0.f;
    if (sl == 0) {
      const float y = acc + bias + gvp;
      const float s = 1.f / (1.f + __expf((gate == 2) ? (-2.f * y) : (-y)));
      act = (gate == 2) ? (2.f * s - 1.f) : s;     // tanh(y) = 2*sigmoid(2y)-1
    }
    const float aI = __shfl(act, 16, 64);
    const float aC = __shfl(act, 32, 64);
    const float aO = __shfl(act, 48, 64);
    if (lane == 0) {
      creg = act * creg + aI * aC;                 // f*c + i*c_new
      const float th = 1.f - 2.f / (1.f + __expf(2.f * creg));
      const float hv = aO * th;
      const uint32 tb = (__float_as_uint(hv) & 0xFFFFFF00u) | ((uint32)(t + 1) & 0xFFu);
      __hip_atomic_store(&hbuf[(size_t)((t + 1) & 1) * DIMS + jr], tb,
                         __ATOMIC_RELAXED, __HIP_MEMORY_SCOPE_AGENT);
    }
    if (sl == 0) {                                 // prefetch gate preact for t+1
      const int tn = (t + 1 < T_SEQ) ? t + 1 : T_SEQ - 1;
      gvp = G[((size_t)tokens[tn] * DIMS + jr) * 4 + gate];
    }
    // (W) rotating coalesced hs writer, post-publish (parity-safe until t+2).
    if ((int)blockIdx.x == (t & 255)) {
      float4 hv4 = h4[t & 1][tid];
      store_h4<HS>(hs, (size_t)t * DIMS + 4 * (size_t)tid, hv4);
    }
  }
}

// ---------------------------------------------------------------- logits = hs @ V.T + bv
template <typename HS> __device__ __forceinline__ void load8(const HS* p, float* o);
template <> __device__ __forceinline__ void load8<float>(const float* p, float* o) {
  float4 a = ((const float4*)p)[0], b = ((const float4*)p)[1];
  o[0]=a.x; o[1]=a.y; o[2]=a.z; o[3]=a.w; o[4]=b.x; o[5]=b.y; o[6]=b.z; o[7]=b.w;
}
template <> __device__ __forceinline__ void load8<u16>(const u16* p, float* o) {
  uint4 u = *(const uint4*)p;
  o[0]=lo2f(u.x); o[1]=hi2f(u.x); o[2]=lo2f(u.y); o[3]=hi2f(u.y);
  o[4]=lo2f(u.z); o[5]=hi2f(u.z); o[6]=lo2f(u.w); o[7]=hi2f(u.w);
}

template <typename HS>
__global__ __launch_bounds__(256) void k_out_gemm(const HS* __restrict__ hs,
                                                  const float* __restrict__ V,
                                                  const float* __restrict__ bvb,
                                                  float* __restrict__ logits) {
  __shared__ float As[32][64];
  __shared__ float Bs[32][128];
  const int t0 = blockIdx.x * 64;
  const int v0 = blockIdx.y * 128;
  const int tid = threadIdx.x;
  const int tx = tid & 15, ty = tid >> 4;
  float acc[4][8] = {{0.f}};
  for (int k0 = 0; k0 < DIMS; k0 += 32) {
    {
      const int r = tid >> 2, q = tid & 3;
      float o8[8];
      load8<HS>(hs + (size_t)(t0 + r) * DIMS + k0 + q * 8, o8);
      #pragma unroll
      for (int s = 0; s < 8; ++s) As[q*8+s][r] = o8[s];
      const int rb = tid >> 1, c0 = (tid & 1) * 2;
      #pragma unroll
      for (int c = 0; c < 2; ++c) {
        float p8[8];
        load8<float>(V + (size_t)(v0 + rb) * DIMS + k0 + (c0 + c) * 8, p8);
        #pragma unroll
        for (int s = 0; s < 8; ++s) Bs[(c0+c)*8+s][rb] = p8[s];
      }
    }
    __syncthreads();
    #pragma unroll
    for (int k = 0; k < 32; ++k) {
      float av[4], bw8[8];
      *(float4*)av = *(const float4*)&As[k][ty*4];
      *(float4*)&bw8[0] = *(const float4*)&Bs[k][tx*8];
      *(float4*)&bw8[4] = *(const float4*)&Bs[k][tx*8+4];
      #pragma unroll
      for (int a = 0; a < 4; ++a)
        #pragma unroll
        for (int b = 0; b < 8; ++b)
          acc[a][b] = fmaf(av[a], bw8[b], acc[a][b]);
    }
    __syncthreads();
  }
  #pragma unroll
  for (int a = 0; a < 4; ++a)
    #pragma unroll
    for (int b = 0; b < 8; ++b)
      logits[(size_t)(t0 + ty*4 + a) * VOCAB + v0 + tx*8 + b] =
          acc[a][b] + bvb[v0 + tx*8 + b];
}

// ---------------------------------------------------------------- log_softmax rows (in-place)
__global__ __launch_bounds__(256) void k_logsoftmax(float* __restrict__ logits) {
  const int t = blockIdx.x;
  const int tid = threadIdx.x;
  float* row = logits + (size_t)t * VOCAB;
  float x0 = row[tid], x1 = row[tid + 256];
  float m = fmaxf(x0, x1);
  #pragma unroll
  for (int d = 32; d; d >>= 1) m = fmaxf(m, __shfl_xor(m, d, 64));
  __shared__ float r1[4], r2[4];
  if ((tid & 63) == 0) r1[tid >> 6] = m;
  __syncthreads();
  m = fmaxf(fmaxf(r1[0], r1[1]), fmaxf(r1[2], r1[3]));
  float s = __expf(x0 - m) + __expf(x1 - m);
  #pragma unroll
  for (int d = 32; d; d >>= 1) s += __shfl_xor(s, d, 64);
  if ((tid & 63) == 0) r2[tid >> 6] = s;
  __syncthreads();
  s = r2[0] + r2[1] + r2[2] + r2[3];
  const float lse = m + __logf(s);
  row[tid] = x0 - lse;
  row[tid + 256] = x1 - lse;
}

// ----------------------------------------------------------------
extern "C" void kernel_launch(void* const* d_in, const int* in_sizes, int n_in,
                              void* d_out, int out_size, void* d_ws, size_t ws_size,
                              hipStream_t stream) {
  const int*   tokens = (const int*)d_in[0];
  const float* Wx  = (const float*)d_in[1];
  const float* bx  = (const float*)d_in[2];
  const float* Uf  = (const float*)d_in[3];
  const float* bUf = (const float*)d_in[4];
  const float* Wf  = (const float*)d_in[5];
  const float* bwf = (const float*)d_in[6];
  const float* Ui  = (const float*)d_in[7];
  const float* bUi = (const float*)d_in[8];
  const float* Wi  = (const float*)d_in[9];
  const float* bwi = (const float*)d_in[10];
  const float* Uc  = (const float*)d_in[11];
  const float* bUc = (const float*)d_in[12];
  const float* Wc  = (const float*)d_in[13];
  const float* bwc = (const float*)d_in[14];
  const float* Uo  = (const float*)d_in[15];
  const float* bUo = (const float*)d_in[16];
  const float* Wo  = (const float*)d_in[17];
  const float* bwo = (const float*)d_in[18];
  const float* V   = (const float*)d_in[19];
  const float* bv  = (const float*)d_in[20];

  char* ws = (char*)d_ws;
  float* X = (float*)ws;                                   // 4 MiB
  float* G = (float*)(ws + 4194304ull);                    // 16 MiB (gate-interleaved)
  uint32* hbuf = (uint32*)(ws + 20971520ull);              // 16 KiB (32 reserved)
  char* rest = ws + 21004288ull;
  const bool f32path = ws_size >= 88113152ull;             // + hs f32 (64 MiB)

  k_build_x<<<dim3((DIMS * VOCAB) / 256), dim3(256), 0, stream>>>(Wx, bx, X);
  dim3 gg(DIMS / 64, VOCAB / 64);
  k_gate_gemm<<<gg, dim3(256), 0, stream>>>(X, Wf, bwf, G, 0);
  k_gate_gemm<<<gg, dim3(256), 0, stream>>>(X, Wi, bwi, G, 1);
  k_gate_gemm<<<gg, dim3(256), 0, stream>>>(X, Wc, bwc, G, 2);
  k_gate_gemm<<<gg, dim3(256), 0, stream>>>(X, Wo, bwo, G, 3);

  float* logits = (float*)d_out;   // logits built in d_out, log_softmax in-place
  if (f32path) {
    float* hs = (float*)rest;
    k_lstm<float><<<dim3(256), dim3(512), 0, stream>>>(
        tokens, G, hbuf, hs, Uf, Ui, Uc, Uo, bUf, bUi, bUc, bUo);
    k_out_gemm<float><<<dim3(T_SEQ / 64, VOCAB / 128), dim3(256), 0, stream>>>(
        hs, V, bv, logits);
  } else {
    u16* hs = (u16*)rest;
    k_lstm<u16><<<dim3(256), dim3(512), 0, stream>>>(
        tokens, G, hbuf, hs, Uf, Ui, Uc, Uo, bUf, bUi, bUc, bUo);
    k_out_gemm<u16><<<dim3(T_SEQ / 64, VOCAB / 128), dim3(256), 0, stream>>>(
        hs, V, bv, logits);
  }
  k_logsoftmax<<<dim3(T_SEQ), dim3(256), 0, stream>>>(logits);
}

// Round 6
// 19469.531 us; speedup vs baseline: 2.8237x; 2.2675x over previous
//
#include <hip/hip_runtime.h>
#include <hip/hip_bf16.h>
#include <stdint.h>

#define T_SEQ 8192
#define DIMS  2048
#define VOCAB 512
#define GS    ((size_t)VOCAB * DIMS)

typedef unsigned short u16;
typedef unsigned int   uint32;
typedef unsigned long long u64;

__device__ __forceinline__ float lo2f(uint32 u) { return __uint_as_float(u << 16); }
__device__ __forceinline__ float hi2f(uint32 u) { return __uint_as_float(u & 0xffff0000u); }

// ---------------------------------------------------------------- X = Wx.T + bx
__global__ __launch_bounds__(256) void k_build_x(const float* __restrict__ Wx,
                                                 const float* __restrict__ bx,
                                                 float* __restrict__ X) {
  int i = blockIdx.x * 256 + threadIdx.x;      // i = d*VOCAB + v
  int v = i & (VOCAB - 1);
  int d = i >> 9;
  X[(size_t)v * DIMS + d] = Wx[i] + bx[d];
}

// ---------------------------------------------------------------- G_g = X @ Wg.T + bwg
// Output interleaved by gate: G[(v*DIMS + j)*4 + gate].
__global__ __launch_bounds__(256) void k_gate_gemm(const float* __restrict__ X,
                                                   const float* __restrict__ Wg,
                                                   const float* __restrict__ bw,
                                                   float* __restrict__ Gout,
                                                   int gate) {
  __shared__ float Xs[32][64];
  __shared__ float Ws[32][64];
  const int v0 = blockIdx.y * 64;
  const int j0 = blockIdx.x * 64;
  const int tid = threadIdx.x;
  const int tx = tid & 15, ty = tid >> 4;
  float acc[4][4] = {{0.f}};
  for (int k0 = 0; k0 < DIMS; k0 += 32) {
    const int r = tid >> 2, q = tid & 3;
    {
      const float* src = X + (size_t)(v0 + r) * DIMS + k0 + q * 8;
      float4 a = ((const float4*)src)[0];
      float4 b = ((const float4*)src)[1];
      Xs[q*8+0][r]=a.x; Xs[q*8+1][r]=a.y; Xs[q*8+2][r]=a.z; Xs[q*8+3][r]=a.w;
      Xs[q*8+4][r]=b.x; Xs[q*8+5][r]=b.y; Xs[q*8+6][r]=b.z; Xs[q*8+7][r]=b.w;
      const float* wsrc = Wg + (size_t)(j0 + r) * DIMS + k0 + q * 8;
      float4 c = ((const float4*)wsrc)[0];
      float4 e = ((const float4*)wsrc)[1];
      Ws[q*8+0][r]=c.x; Ws[q*8+1][r]=c.y; Ws[q*8+2][r]=c.z; Ws[q*8+3][r]=c.w;
      Ws[q*8+4][r]=e.x; Ws[q*8+5][r]=e.y; Ws[q*8+6][r]=e.z; Ws[q*8+7][r]=e.w;
    }
    __syncthreads();
    #pragma unroll
    for (int k = 0; k < 32; ++k) {
      float xa[4], wb[4];
      *(float4*)xa = *(const float4*)&Xs[k][ty*4];
      *(float4*)wb = *(const float4*)&Ws[k][tx*4];
      #pragma unroll
      for (int a = 0; a < 4; ++a)
        #pragma unroll
        for (int b = 0; b < 4; ++b)
          acc[a][b] = fmaf(xa[a], wb[b], acc[a][b]);
    }
    __syncthreads();
  }
  #pragma unroll
  for (int a = 0; a < 4; ++a)
    #pragma unroll
    for (int b = 0; b < 4; ++b)
      Gout[(((size_t)(v0 + ty*4 + a) * DIMS + j0 + tx*4 + b) << 2) + gate] =
          acc[a][b] + bw[j0 + tx*4 + b];
}

// ---------------------------------------------------------------- recurrence
// Round-9: EXACT revert to the round-1 kernel (K1, best: 18.7ms k_lstm).
// Ledger of failed perturbations (all reverted):
//  - dot restructure to 8 contiguous b128/lane (+43%)
//  - per-XCD mirror hop (+96%: one extra publish->discover round trip ~2.2us)
//  - DPP row_shr tail + lane-15 publisher (regressed twice)
//  - returning atomic publish (atomic_swap starved vs 2048 read-sharers, +170%)
//  - hs writer after publish (+130%: the next poll's vmcnt wait drains the
//    writer's 8KB of stores; in K1 they drain hidden under the dot)
// K1's steady state: step = publish->L3->discover round trip (~4kcy) + dot/tail
// (~1.5kcy). Writer-before-dot is load-bearing: stores drain under the dot.
template <typename HS> __device__ __forceinline__ void store_h4(HS* hs, size_t idx, float4 v);
template <> __device__ __forceinline__ void store_h4<float>(float* hs, size_t idx, float4 v) {
  *(float4*)(hs + idx) = v;
}
template <> __device__ __forceinline__ void store_h4<u16>(u16* hs, size_t idx, float4 v) {
  __hip_bfloat16 bx = __float2bfloat16(v.x);
  __hip_bfloat16 by = __float2bfloat16(v.y);
  __hip_bfloat16 bz = __float2bfloat16(v.z);
  __hip_bfloat16 bw = __float2bfloat16(v.w);
  ushort4 o;
  o.x = *reinterpret_cast<u16*>(&bx);
  o.y = *reinterpret_cast<u16*>(&by);
  o.z = *reinterpret_cast<u16*>(&bz);
  o.w = *reinterpret_cast<u16*>(&bw);
  *(ushort4*)(hs + idx) = o;
}

template <typename HS>
__global__ __launch_bounds__(512, 2) void k_lstm(
    const int* __restrict__ tokens,
    const float* __restrict__ G,
    uint32* hbuf,
    HS* __restrict__ hs,
    const float* __restrict__ Uf, const float* __restrict__ Ui,
    const float* __restrict__ Uc, const float* __restrict__ Uo,
    const float* __restrict__ bUf, const float* __restrict__ bUi,
    const float* __restrict__ bUc, const float* __restrict__ bUo) {
  __shared__ float4 h4[2][DIMS / 4];
  const int tid  = threadIdx.x;          // 0..511
  const int wave = tid >> 6;             // 0..7
  const int lane = tid & 63;
  const int gate = lane >> 4;            // 0..3 -> f,i,c,o
  const int sl   = lane & 15;            // k-split within gate group
  const int jr   = blockIdx.x * 8 + wave;

  const float* Ug = (gate == 0) ? Uf : (gate == 1) ? Ui : (gate == 2) ? Uc : Uo;
  const float4* urow = (const float4*)(Ug + (size_t)jr * DIMS);
  float4 w[32];
  #pragma unroll
  for (int i = 0; i < 32; ++i) w[i] = urow[sl + 16 * i];
  #pragma unroll
  for (int i = 0; i < 32; ++i)
    asm volatile("" : "+v"(w[i].x), "+v"(w[i].y), "+v"(w[i].z), "+v"(w[i].w));

  float creg = 0.f, bias = 0.f, gvp = 0.f;
  if (sl == 0) {   // lanes 0,16,32,48 own one gate each
    const float* Bg = (gate == 0) ? bUf : (gate == 1) ? bUi : (gate == 2) ? bUc : bUo;
    bias = Bg[jr];
    const int tok0 = tokens[0];
    gvp = G[((size_t)tok0 * DIMS + jr) * 4 + gate];
  }
  if (lane == 0) {
    // h0 = 0 with tag 0; buffer-1 tag 0 (!= 1, != poison 0xAA).
    __hip_atomic_store(&hbuf[jr], 0u, __ATOMIC_RELAXED, __HIP_MEMORY_SCOPE_AGENT);
    __hip_atomic_store(&hbuf[DIMS + jr], 0u, __ATOMIC_RELAXED, __HIP_MEMORY_SCOPE_AGENT);
  }

  #pragma unroll 1
  for (int t = 0; t < T_SEQ; ++t) {
    { // stage h_t: thread tid owns h[4*tid..4*tid+3]; poll tags, selective retry
      const u64* hsrc = (const u64*)(hbuf + (size_t)(t & 1) * DIMS) + 2 * tid;
      const uint32 want = (uint32)t & 0xFFu;
      u64 u0 = __hip_atomic_load(hsrc + 0, __ATOMIC_RELAXED, __HIP_MEMORY_SCOPE_AGENT);
      u64 u1 = __hip_atomic_load(hsrc + 1, __ATOMIC_RELAXED, __HIP_MEMORY_SCOPE_AGENT);
      for (;;) {
        const bool ok0 = ((((uint32)u0 ^ want) | ((uint32)(u0 >> 32) ^ want)) & 0xFFu) == 0u;
        const bool ok1 = ((((uint32)u1 ^ want) | ((uint32)(u1 >> 32) ^ want)) & 0xFFu) == 0u;
        if (ok0 && ok1) break;
        if (!ok0) u0 = __hip_atomic_load(hsrc + 0, __ATOMIC_RELAXED, __HIP_MEMORY_SCOPE_AGENT);
        if (!ok1) u1 = __hip_atomic_load(hsrc + 1, __ATOMIC_RELAXED, __HIP_MEMORY_SCOPE_AGENT);
      }
      h4[t & 1][tid] = make_float4(__uint_as_float((uint32)u0),
                                   __uint_as_float((uint32)(u0 >> 32)),
                                   __uint_as_float((uint32)u1),
                                   __uint_as_float((uint32)(u1 >> 32)));
    }
    __syncthreads();
    // rotating coalesced hs writer: one block per step, from staged LDS.
    // Placed BEFORE the dot so the 8KB of stores drain under the ~1000cy dot
    // (placing them later makes the next poll's vmcnt wait drain them: +130%).
    if ((int)blockIdx.x == (t & 255)) {
      float4 hv4 = h4[t & 1][tid];
      store_h4<HS>(hs, (size_t)t * DIMS + 4 * (size_t)tid, hv4);
    }
    // one dot of length 2048, split: gate group reads all h, sub-lane covers 128 k
    const float4* hb = h4[t & 1];
    float4 a4 = make_float4(0.f, 0.f, 0.f, 0.f);
    #pragma unroll
    for (int i = 0; i < 32; ++i) {
      float4 hv = hb[sl + 16 * i];
      a4.x = fmaf(w[i].x, hv.x, a4.x);
      a4.y = fmaf(w[i].y, hv.y, a4.y);
      a4.z = fmaf(w[i].z, hv.z, a4.z);
      a4.w = fmaf(w[i].w, hv.w, a4.w);
    }
    float acc = (a4.x + a4.y) + (a4.z + a4.w);
    #pragma unroll
    for (int d = 1; d <= 8; d <<= 1) acc += __shfl_xor(acc, d, 64);
    // per-gate activation in parallel on lanes 0,16,32,48
    float act = 0.f;
    if (sl == 0) {
      const float y = acc + bias + gvp;
      const float s = 1.f / (1.f + __expf((gate == 2) ? (-2.f * y) : (-y)));
      act = (gate == 2) ? (2.f * s - 1.f) : s;     // tanh(y) = 2*sigmoid(2y)-1
    }
    const float aI = __shfl(act, 16, 64);
    const float aC = __shfl(act, 32, 64);
    const float aO = __shfl(act, 48, 64);
    if (lane == 0) {
      creg = act * creg + aI * aC;                 // f*c + i*c_new
      const float th = 1.f - 2.f / (1.f + __expf(2.f * creg));
      const float hv = aO * th;
      const uint32 tb = (__float_as_uint(hv) & 0xFFFFFF00u) | ((uint32)(t + 1) & 0xFFu);
      __hip_atomic_store(&hbuf[(size_t)((t + 1) & 1) * DIMS + jr], tb,
                         __ATOMIC_RELAXED, __HIP_MEMORY_SCOPE_AGENT);
    }
    if (sl == 0) {                                 // prefetch gate preact for t+1
      const int tn = (t + 1 < T_SEQ) ? t + 1 : T_SEQ - 1;
      gvp = G[((size_t)tokens[tn] * DIMS + jr) * 4 + gate];
    }
  }
}

// ---------------------------------------------------------------- logits = hs @ V.T + bv
template <typename HS> __device__ __forceinline__ void load8(const HS* p, float* o);
template <> __device__ __forceinline__ void load8<float>(const float* p, float* o) {
  float4 a = ((const float4*)p)[0], b = ((const float4*)p)[1];
  o[0]=a.x; o[1]=a.y; o[2]=a.z; o[3]=a.w; o[4]=b.x; o[5]=b.y; o[6]=b.z; o[7]=b.w;
}
template <> __device__ __forceinline__ void load8<u16>(const u16* p, float* o) {
  uint4 u = *(const uint4*)p;
  o[0]=lo2f(u.x); o[1]=hi2f(u.x); o[2]=lo2f(u.y); o[3]=hi2f(u.y);
  o[4]=lo2f(u.z); o[5]=hi2f(u.z); o[6]=lo2f(u.w); o[7]=hi2f(u.w);
}

template <typename HS>
__global__ __launch_bounds__(256) void k_out_gemm(const HS* __restrict__ hs,
                                                  const float* __restrict__ V,
                                                  const float* __restrict__ bvb,
                                                  float* __restrict__ logits) {
  __shared__ float As[32][64];
  __shared__ float Bs[32][128];
  const int t0 = blockIdx.x * 64;
  const int v0 = blockIdx.y * 128;
  const int tid = threadIdx.x;
  const int tx = tid & 15, ty = tid >> 4;
  float acc[4][8] = {{0.f}};
  for (int k0 = 0; k0 < DIMS; k0 += 32) {
    {
      const int r = tid >> 2, q = tid & 3;
      float o8[8];
      load8<HS>(hs + (size_t)(t0 + r) * DIMS + k0 + q * 8, o8);
      #pragma unroll
      for (int s = 0; s < 8; ++s) As[q*8+s][r] = o8[s];
      const int rb = tid >> 1, c0 = (tid & 1) * 2;
      #pragma unroll
      for (int c = 0; c < 2; ++c) {
        float p8[8];
        load8<float>(V + (size_t)(v0 + rb) * DIMS + k0 + (c0 + c) * 8, p8);
        #pragma unroll
        for (int s = 0; s < 8; ++s) Bs[(c0+c)*8+s][rb] = p8[s];
      }
    }
    __syncthreads();
    #pragma unroll
    for (int k = 0; k < 32; ++k) {
      float av[4], bw8[8];
      *(float4*)av = *(const float4*)&As[k][ty*4];
      *(float4*)&bw8[0] = *(const float4*)&Bs[k][tx*8];
      *(float4*)&bw8[4] = *(const float4*)&Bs[k][tx*8+4];
      #pragma unroll
      for (int a = 0; a < 4; ++a)
        #pragma unroll
        for (int b = 0; b < 8; ++b)
          acc[a][b] = fmaf(av[a], bw8[b], acc[a][b]);
    }
    __syncthreads();
  }
  #pragma unroll
  for (int a = 0; a < 4; ++a)
    #pragma unroll
    for (int b = 0; b < 8; ++b)
      logits[(size_t)(t0 + ty*4 + a) * VOCAB + v0 + tx*8 + b] =
          acc[a][b] + bvb[v0 + tx*8 + b];
}

// ---------------------------------------------------------------- log_softmax rows (in-place)
__global__ __launch_bounds__(256) void k_logsoftmax(float* __restrict__ logits) {
  const int t = blockIdx.x;
  const int tid = threadIdx.x;
  float* row = logits + (size_t)t * VOCAB;
  float x0 = row[tid], x1 = row[tid + 256];
  float m = fmaxf(x0, x1);
  #pragma unroll
  for (int d = 32; d; d >>= 1) m = fmaxf(m, __shfl_xor(m, d, 64));
  __shared__ float r1[4], r2[4];
  if ((tid & 63) == 0) r1[tid >> 6] = m;
  __syncthreads();
  m = fmaxf(fmaxf(r1[0], r1[1]), fmaxf(r1[2], r1[3]));
  float s = __expf(x0 - m) + __expf(x1 - m);
  #pragma unroll
  for (int d = 32; d; d >>= 1) s += __shfl_xor(s, d, 64);
  if ((tid & 63) == 0) r2[tid >> 6] = s;
  __syncthreads();
  s = r2[0] + r2[1] + r2[2] + r2[3];
  const float lse = m + __logf(s);
  row[tid] = x0 - lse;
  row[tid + 256] = x1 - lse;
}

// ----------------------------------------------------------------
extern "C" void kernel_launch(void* const* d_in, const int* in_sizes, int n_in,
                              void* d_out, int out_size, void* d_ws, size_t ws_size,
                              hipStream_t stream) {
  const int*   tokens = (const int*)d_in[0];
  const float* Wx  = (const float*)d_in[1];
  const float* bx  = (const float*)d_in[2];
  const float* Uf  = (const float*)d_in[3];
  const float* bUf = (const float*)d_in[4];
  const float* Wf  = (const float*)d_in[5];
  const float* bwf = (const float*)d_in[6];
  const float* Ui  = (const float*)d_in[7];
  const float* bUi = (const float*)d_in[8];
  const float* Wi  = (const float*)d_in[9];
  const float* bwi = (const float*)d_in[10];
  const float* Uc  = (const float*)d_in[11];
  const float* bUc = (const float*)d_in[12];
  const float* Wc  = (const float*)d_in[13];
  const float* bwc = (const float*)d_in[14];
  const float* Uo  = (const float*)d_in[15];
  const float* bUo = (const float*)d_in[16];
  const float* Wo  = (const float*)d_in[17];
  const float* bwo = (const float*)d_in[18];
  const float* V   = (const float*)d_in[19];
  const float* bv  = (const float*)d_in[20];

  char* ws = (char*)d_ws;
  float* X = (float*)ws;                                   // 4 MiB
  float* G = (float*)(ws + 4194304ull);                    // 16 MiB (gate-interleaved)
  uint32* hbuf = (uint32*)(ws + 20971520ull);              // 16 KiB (32 reserved)
  char* rest = ws + 21004288ull;
  const bool f32path = ws_size >= 88113152ull;             // + hs f32 (64 MiB)

  k_build_x<<<dim3((DIMS * VOCAB) / 256), dim3(256), 0, stream>>>(Wx, bx, X);
  dim3 gg(DIMS / 64, VOCAB / 64);
  k_gate_gemm<<<gg, dim3(256), 0, stream>>>(X, Wf, bwf, G, 0);
  k_gate_gemm<<<gg, dim3(256), 0, stream>>>(X, Wi, bwi, G, 1);
  k_gate_gemm<<<gg, dim3(256), 0, stream>>>(X, Wc, bwc, G, 2);
  k_gate_gemm<<<gg, dim3(256), 0, stream>>>(X, Wo, bwo, G, 3);

  float* logits = (float*)d_out;   // logits built in d_out, log_softmax in-place
  if (f32path) {
    float* hs = (float*)rest;
    k_lstm<float><<<dim3(256), dim3(512), 0, stream>>>(
        tokens, G, hbuf, hs, Uf, Ui, Uc, Uo, bUf, bUi, bUc, bUo);
    k_out_gemm<float><<<dim3(T_SEQ / 64, VOCAB / 128), dim3(256), 0, stream>>>(
        hs, V, bv, logits);
  } else {
    u16* hs = (u16*)rest;
    k_lstm<u16><<<dim3(256), dim3(512), 0, stream>>>(
        tokens, G, hbuf, hs, Uf, Ui, Uc, Uo, bUf, bUi, bUc, bUo);
    k_out_gemm<u16><<<dim3(T_SEQ / 64, VOCAB / 128), dim3(256), 0, stream>>>(
        hs, V, bv, logits);
  }
  k_logsoftmax<<<dim3(T_SEQ), dim3(256), 0, stream>>>(logits);
}